// Round 5
// baseline (285.264 us; speedup 1.0000x reference)
//
#include <hip/hip_runtime.h>
#include <math.h>

#define N_TOKENS 16384
#define D_MODEL 2048
#define NUM_EXPERTS 64
#define TOPK 8
#define BLOCK_THREADS 512           // 8 waves: 4 token-groups x 2 roles
#define T_PER_GROUP 8
#define TOK_PER_BLOCK 32
#define NSTEP4 (D_MODEL / 4)        // 512 float4 steps per row

__device__ __forceinline__ float f4c(const float4& v, int j) {
    return j == 0 ? v.x : j == 1 ? v.y : j == 2 ? v.z : v.w;
}

// Pre-pass: WT4[kk][col] (col = role*64 + e) = {W_role[4kk+j][e], j=0..3}
// so the main loop's W read is one coalesced dwordx4 per 4 k's per lane.
__global__ __launch_bounds__(256)
void wt_build_kernel(const float* __restrict__ Wg, const float* __restrict__ Wn,
                     float4* __restrict__ WT4) {
    const int id  = blockIdx.x * 256 + threadIdx.x;    // 0..65535
    const int kk  = id >> 7;
    const int col = id & 127;
    const int ro  = col >> 6;
    const int e   = col & 63;
    const float* src = (ro ? Wn : Wg) + (size_t)(kk * 4) * NUM_EXPERTS + e;
    WT4[id] = make_float4(src[0], src[NUM_EXPERTS], src[2 * NUM_EXPERTS], src[3 * NUM_EXPERTS]);
}

__global__ __launch_bounds__(BLOCK_THREADS, 4)
void noisy_topk_router_kernel(const float* __restrict__ x,
                              const float* __restrict__ eps,
                              const float4* __restrict__ WT4,
                              const float* __restrict__ bg,
                              const float* __restrict__ bn,
                              float* __restrict__ out_probs,
                              float* __restrict__ out_idx)
{
    __shared__ double exbuf[2][TOK_PER_BLOCK][NUM_EXPERTS];   // 32 KB

    const int tid  = threadIdx.x;
    const int lane = tid & 63;
    const int w    = __builtin_amdgcn_readfirstlane(tid >> 6);  // wave id (uniform)
    const int gi   = w >> 1;          // token group 0..3
    const int ro   = w & 1;           // 0 = gate, 1 = noise
    const int btok0 = blockIdx.x * TOK_PER_BLOCK;
    const int tok0  = btok0 + gi * T_PER_GROUP;

    const float4* xb[T_PER_GROUP];
    #pragma unroll
    for (int t = 0; t < T_PER_GROUP; ++t)
        xb[t] = reinterpret_cast<const float4*>(x) + (size_t)(tok0 + t) * NSTEP4;

    // this wave's W stream: one float4 (4 k's) per step, coalesced across lanes
    const float4* wtp = WT4 + ro * 64 + lane;   // advance by 128 float4 per step

    float  ag[T_PER_GROUP];
    double dd[T_PER_GROUP];
    #pragma unroll
    for (int t = 0; t < T_PER_GROUP; ++t) { ag[t] = 0.f; dd[t] = 0.0; }

    // 64 half-spans of 32 k (8 float4-steps); fp64 fold + convoy barrier per span
    for (int h = 0; h < 64; ++h) {
        const int i0 = h * 8;
        #pragma unroll
        for (int s = 0; s < 8; ++s) {
            const int i = i0 + s;
            const float4 wt = wtp[(size_t)i * 128];
            float4 xv[T_PER_GROUP];
            #pragma unroll
            for (int t = 0; t < T_PER_GROUP; ++t) xv[t] = xb[t][i];
            #pragma unroll
            for (int j = 0; j < 4; ++j) {
                const float wj = f4c(wt, j);
                #pragma unroll
                for (int t = 0; t < T_PER_GROUP; ++t)
                    ag[t] = fmaf(f4c(xv[t], j), wj, ag[t]);
            }
        }
        #pragma unroll
        for (int t = 0; t < T_PER_GROUP; ++t) { dd[t] += (double)ag[t]; ag[t] = 0.f; }
        __builtin_amdgcn_s_barrier();   // convoy only — no LDS/global deps here
    }

    // exchange: role 0 deposits gate dots, role 1 noise dots
    #pragma unroll
    for (int t = 0; t < T_PER_GROUP; ++t)
        exbuf[ro][gi * T_PER_GROUP + t][lane] = dd[t];
    __syncthreads();

    // epilogue: each wave finishes 4 tokens (softplus + noise + top-8 + softmax)
    const float bgv = bg[lane];
    const float bnv = bn[lane];

    #pragma unroll 1
    for (int q = 0; q < 4; ++q) {
        const int tt  = w * 4 + q;
        const int tok = btok0 + tt;
        const double logit = exbuf[0][tt][lane] + (double)bgv;
        const double nvv   = exbuf[1][tt][lane] + (double)bnv;
        const double sp    = (nvv > 0.0) ? (nvv + log1p(exp(-nvv))) : log1p(exp(nvv));
        const double noisy = logit + (double)eps[(size_t)tok * NUM_EXPERTS + lane] * sp;

        // iterative top-8; tie-break: higher value, then lower index (lax.top_k)
        double cur = noisy;
        double m = 0.0, sum = 0.0;
        int    sel = 0;
        float  my_idx = 0.0f;
        #pragma unroll
        for (int rk = 0; rk < TOPK; ++rk) {
            double bv = cur;
            int    bi = lane;
            #pragma unroll
            for (int off = 32; off >= 1; off >>= 1) {
                double ov = __shfl_xor(bv, off);
                int    oi = __shfl_xor(bi, off);
                if (ov > bv || (ov == bv && oi < bi)) { bv = ov; bi = oi; }
            }
            if (rk == 0) m = bv;
            sum += exp(bv - m);
            if (lane == bi) { sel = 1; cur = -INFINITY; }
            if (lane == rk) my_idx = (float)bi;
        }

        out_probs[(size_t)tok * NUM_EXPERTS + lane] = (float)(sel ? exp(noisy - m) / sum : 0.0);
        if (lane < TOPK) out_idx[(size_t)tok * TOPK + lane] = my_idx;
    }
}

extern "C" void kernel_launch(void* const* d_in, const int* in_sizes, int n_in,
                              void* d_out, int out_size, void* d_ws, size_t ws_size,
                              hipStream_t stream) {
    const float* x   = (const float*)d_in[0];
    const float* eps = (const float*)d_in[1];
    const float* Wg  = (const float*)d_in[2];
    const float* bg  = (const float*)d_in[3];
    const float* Wn  = (const float*)d_in[4];
    const float* bn  = (const float*)d_in[5];

    float* out_probs = (float*)d_out;                                  // [N, E]
    float* out_idx   = (float*)d_out + (size_t)N_TOKENS * NUM_EXPERTS; // [N, K]

    float4* WT4 = (float4*)d_ws;    // 512 * 128 * 16 B = 1 MB

    wt_build_kernel<<<dim3(256), dim3(256), 0, stream>>>(Wg, Wn, WT4);

    dim3 grid(N_TOKENS / TOK_PER_BLOCK);   // 512
    dim3 block(BLOCK_THREADS);             // 512
    noisy_topk_router_kernel<<<grid, block, 0, stream>>>(
        x, eps, WT4, bg, bn, out_probs, out_idx);
}

// Round 6
// 285.229 us; speedup vs baseline: 1.0001x; 1.0001x over previous
//
#include <hip/hip_runtime.h>
#include <math.h>

#define N_TOKENS 16384
#define D_MODEL 2048
#define NUM_EXPERTS 64
#define TOPK 8
#define BLOCK_THREADS 512           // 8 waves: 4 token-groups x 2 roles
#define T_PER_GROUP 8
#define TOK_PER_BLOCK 32
#define NSTEP4 (D_MODEL / 4)        // 512 float4 steps per row

__device__ __forceinline__ float f4c(const float4& v, int j) {
    return j == 0 ? v.x : j == 1 ? v.y : j == 2 ? v.z : v.w;
}

// Pre-pass: WT4[kk][col] (col = role*64 + e) = {W_role[4kk+j][e], j=0..3}
// so the main loop's W read is one coalesced dwordx4 per 4 k's per lane.
__global__ __launch_bounds__(256)
void wt_build_kernel(const float* __restrict__ Wg, const float* __restrict__ Wn,
                     float4* __restrict__ WT4) {
    const int id  = blockIdx.x * 256 + threadIdx.x;    // 0..65535
    const int kk  = id >> 7;
    const int col = id & 127;
    const int ro  = col >> 6;
    const int e   = col & 63;
    const float* src = (ro ? Wn : Wg) + (size_t)(kk * 4) * NUM_EXPERTS + e;
    WT4[id] = make_float4(src[0], src[NUM_EXPERTS], src[2 * NUM_EXPERTS], src[3 * NUM_EXPERTS]);
}

__global__ __launch_bounds__(BLOCK_THREADS, 4)
void noisy_topk_router_kernel(const float* __restrict__ x,
                              const float* __restrict__ eps,
                              const float4* __restrict__ WT4,
                              const float* __restrict__ bg,
                              const float* __restrict__ bn,
                              float* __restrict__ out_probs,
                              float* __restrict__ out_idx)
{
    __shared__ double exbuf[2][TOK_PER_BLOCK][NUM_EXPERTS];   // 32 KB

    const int tid  = threadIdx.x;
    const int lane = tid & 63;
    const int w    = __builtin_amdgcn_readfirstlane(tid >> 6);  // wave id (uniform)
    const int gi   = w >> 1;          // token group 0..3
    const int ro   = w & 1;           // 0 = gate, 1 = noise
    const int btok0 = blockIdx.x * TOK_PER_BLOCK;
    const int tok0  = btok0 + gi * T_PER_GROUP;

    const float4* xb[T_PER_GROUP];
    #pragma unroll
    for (int t = 0; t < T_PER_GROUP; ++t)
        xb[t] = reinterpret_cast<const float4*>(x) + (size_t)(tok0 + t) * NSTEP4;

    // this wave's W stream: one float4 (4 k's) per step, coalesced across lanes
    const float4* wtp = WT4 + ro * 64 + lane;   // advance by 128 float4 per step

    float  ag[T_PER_GROUP];
    double dd[T_PER_GROUP];
    #pragma unroll
    for (int t = 0; t < T_PER_GROUP; ++t) { ag[t] = 0.f; dd[t] = 0.0; }

    // 64 half-spans of 32 k (8 float4-steps); fp64 fold + convoy barrier per span
    for (int h = 0; h < 64; ++h) {
        const int i0 = h * 8;
        #pragma unroll
        for (int s = 0; s < 8; ++s) {
            const int i = i0 + s;
            const float4 wt = wtp[(size_t)i * 128];
            float4 xv[T_PER_GROUP];
            #pragma unroll
            for (int t = 0; t < T_PER_GROUP; ++t) xv[t] = xb[t][i];
            #pragma unroll
            for (int j = 0; j < 4; ++j) {
                const float wj = f4c(wt, j);
                #pragma unroll
                for (int t = 0; t < T_PER_GROUP; ++t)
                    ag[t] = fmaf(f4c(xv[t], j), wj, ag[t]);
            }
        }
        #pragma unroll
        for (int t = 0; t < T_PER_GROUP; ++t) { dd[t] += (double)ag[t]; ag[t] = 0.f; }
        __builtin_amdgcn_s_barrier();   // convoy only — no LDS/global deps here
    }

    // exchange: role 0 deposits gate dots, role 1 noise dots
    #pragma unroll
    for (int t = 0; t < T_PER_GROUP; ++t)
        exbuf[ro][gi * T_PER_GROUP + t][lane] = dd[t];
    __syncthreads();

    // epilogue: each wave finishes 4 tokens (softplus + noise + top-8 + softmax)
    const float bgv = bg[lane];
    const float bnv = bn[lane];

    #pragma unroll 1
    for (int q = 0; q < 4; ++q) {
        const int tt  = w * 4 + q;
        const int tok = btok0 + tt;
        const double logit = exbuf[0][tt][lane] + (double)bgv;
        const double nvv   = exbuf[1][tt][lane] + (double)bnv;
        const double sp    = (nvv > 0.0) ? (nvv + log1p(exp(-nvv))) : log1p(exp(nvv));
        const double noisy = logit + (double)eps[(size_t)tok * NUM_EXPERTS + lane] * sp;

        // iterative top-8; tie-break: higher value, then lower index (lax.top_k)
        double cur = noisy;
        double m = 0.0, sum = 0.0;
        int    sel = 0;
        float  my_idx = 0.0f;
        #pragma unroll
        for (int rk = 0; rk < TOPK; ++rk) {
            double bv = cur;
            int    bi = lane;
            #pragma unroll
            for (int off = 32; off >= 1; off >>= 1) {
                double ov = __shfl_xor(bv, off);
                int    oi = __shfl_xor(bi, off);
                if (ov > bv || (ov == bv && oi < bi)) { bv = ov; bi = oi; }
            }
            if (rk == 0) m = bv;
            sum += exp(bv - m);
            if (lane == bi) { sel = 1; cur = -INFINITY; }
            if (lane == rk) my_idx = (float)bi;
        }

        out_probs[(size_t)tok * NUM_EXPERTS + lane] = (float)(sel ? exp(noisy - m) / sum : 0.0);
        if (lane < TOPK) out_idx[(size_t)tok * TOPK + lane] = my_idx;
    }
}

extern "C" void kernel_launch(void* const* d_in, const int* in_sizes, int n_in,
                              void* d_out, int out_size, void* d_ws, size_t ws_size,
                              hipStream_t stream) {
    const float* x   = (const float*)d_in[0];
    const float* eps = (const float*)d_in[1];
    const float* Wg  = (const float*)d_in[2];
    const float* bg  = (const float*)d_in[3];
    const float* Wn  = (const float*)d_in[4];
    const float* bn  = (const float*)d_in[5];

    float* out_probs = (float*)d_out;                                  // [N, E]
    float* out_idx   = (float*)d_out + (size_t)N_TOKENS * NUM_EXPERTS; // [N, K]

    float4* WT4 = (float4*)d_ws;    // 512 * 128 * 16 B = 1 MB

    wt_build_kernel<<<dim3(256), dim3(256), 0, stream>>>(Wg, Wn, WT4);

    dim3 grid(N_TOKENS / TOK_PER_BLOCK);   // 512
    dim3 block(BLOCK_THREADS);             // 512
    noisy_topk_router_kernel<<<grid, block, 0, stream>>>(
        x, eps, WT4, bg, bn, out_probs, out_idx);
}

// Round 8
// 229.963 us; speedup vs baseline: 1.2405x; 1.2403x over previous
//
#include <hip/hip_runtime.h>
#include <math.h>

#define N_TOKENS 16384
#define D_MODEL 2048
#define NUM_EXPERTS 64
#define TOPK 8
#define BLOCK_THREADS 512       // 8 waves: 2 k-halves x 2 roles x 2 token-groups
#define T_PER_GROUP 8
#define TOK_PER_BLOCK 16
#define KHALF4 (D_MODEL / 2 / 4)    // 256 float4 steps per wave

__device__ __forceinline__ float f4c(const float4& v, int j) {
    return j == 0 ? v.x : j == 1 ? v.y : j == 2 ? v.z : v.w;
}

// Pre-pass: WT4[kk][col] (col = role*64 + e) = {W_role[4kk+j][e], j=0..3}
// so the main loop's W read is one coalesced dwordx4 per 4 k's per lane.
__global__ __launch_bounds__(256)
void wt_build_kernel(const float* __restrict__ Wg, const float* __restrict__ Wn,
                     float4* __restrict__ WT4) {
    const int id  = blockIdx.x * 256 + threadIdx.x;    // 0..65535
    const int kk  = id >> 7;
    const int col = id & 127;
    const int ro  = col >> 6;
    const int e   = col & 63;
    const float* src = (ro ? Wn : Wg) + (size_t)(kk * 4) * NUM_EXPERTS + e;
    WT4[id] = make_float4(src[0], src[NUM_EXPERTS], src[2 * NUM_EXPERTS], src[3 * NUM_EXPERTS]);
}

__global__ __launch_bounds__(BLOCK_THREADS, 8)
void noisy_topk_router_kernel(const float* __restrict__ x,
                              const float* __restrict__ eps,
                              const float4* __restrict__ WT4,
                              const float* __restrict__ bg,
                              const float* __restrict__ bn,
                              float* __restrict__ out_probs,
                              float* __restrict__ out_idx)
{
    // fp64 partials: [khalf][role][token][expert] = 32 KB
    __shared__ double exbuf[2][2][TOK_PER_BLOCK][NUM_EXPERTS];

    const int tid  = threadIdx.x;
    const int lane = tid & 63;
    const int w    = __builtin_amdgcn_readfirstlane(tid >> 6);
    const int kh   = w & 1;           // k-half: 0 -> k<1024, 1 -> k>=1024
    const int ro   = (w >> 1) & 1;    // 0 = gate, 1 = noise
    const int gi   = w >> 2;          // token group 0..1
    const int btok0 = blockIdx.x * TOK_PER_BLOCK;
    const int tok0  = btok0 + gi * T_PER_GROUP;

    // x pointers, offset to this wave's k-half (addresses are wave-uniform)
    const float4* xb[T_PER_GROUP];
    #pragma unroll
    for (int t = 0; t < T_PER_GROUP; ++t)
        xb[t] = reinterpret_cast<const float4*>(x + (size_t)(tok0 + t) * D_MODEL)
                + kh * KHALF4;

    // W stream for this wave's (k-half, role): one float4 per step, coalesced
    const float4* wtp = WT4 + (size_t)kh * KHALF4 * 128 + ro * 64 + lane;

    float  ag[T_PER_GROUP];
    double dd[T_PER_GROUP];
    #pragma unroll
    for (int t = 0; t < T_PER_GROUP; ++t) { ag[t] = 0.f; dd[t] = 0.0; }

    // 16 iterations of 64 k (16 float4-steps); fp32->fp64 fold every 32 k,
    // convoy barrier every 64 k. Total = 256 float4 steps = this wave's k-half.
    for (int h = 0; h < 16; ++h) {
        #pragma unroll
        for (int half = 0; half < 2; ++half) {
            const int i0 = h * 16 + half * 8;
            #pragma unroll
            for (int s = 0; s < 8; ++s) {
                const int i = i0 + s;
                const float4 wt = wtp[(size_t)i * 128];
                float4 xv[T_PER_GROUP];
                #pragma unroll
                for (int t = 0; t < T_PER_GROUP; ++t) xv[t] = xb[t][i];
                #pragma unroll
                for (int j = 0; j < 4; ++j) {
                    const float wj = f4c(wt, j);
                    #pragma unroll
                    for (int t = 0; t < T_PER_GROUP; ++t)
                        ag[t] = fmaf(f4c(xv[t], j), wj, ag[t]);
                }
            }
            #pragma unroll
            for (int t = 0; t < T_PER_GROUP; ++t) { dd[t] += (double)ag[t]; ag[t] = 0.f; }
        }
        __builtin_amdgcn_s_barrier();   // convoy only — no LDS/global deps here
    }

    // deposit fp64 partials
    #pragma unroll
    for (int t = 0; t < T_PER_GROUP; ++t)
        exbuf[kh][ro][gi * T_PER_GROUP + t][lane] = dd[t];
    __syncthreads();

    // epilogue: each wave finishes 2 tokens (softplus + noise + top-8 + softmax)
    const float bgv = bg[lane];
    const float bnv = bn[lane];

    #pragma unroll 1
    for (int q = 0; q < 2; ++q) {
        const int tt  = w * 2 + q;
        const int tok = btok0 + tt;
        const double logit = (exbuf[0][0][tt][lane] + exbuf[1][0][tt][lane]) + (double)bgv;
        const double nvv   = (exbuf[0][1][tt][lane] + exbuf[1][1][tt][lane]) + (double)bnv;
        const double sp    = (nvv > 0.0) ? (nvv + log1p(exp(-nvv))) : log1p(exp(nvv));
        const double noisy = logit + (double)eps[(size_t)tok * NUM_EXPERTS + lane] * sp;

        // iterative top-8; tie-break: higher value, then lower index (lax.top_k)
        double cur = noisy;
        double m = 0.0, sum = 0.0;
        int    sel = 0;
        float  my_idx = 0.0f;
        #pragma unroll
        for (int rk = 0; rk < TOPK; ++rk) {
            double bv = cur;
            int    bi = lane;
            #pragma unroll
            for (int off = 32; off >= 1; off >>= 1) {
                double ov = __shfl_xor(bv, off);
                int    oi = __shfl_xor(bi, off);
                if (ov > bv || (ov == bv && oi < bi)) { bv = ov; bi = oi; }
            }
            if (rk == 0) m = bv;
            sum += exp(bv - m);
            if (lane == bi) { sel = 1; cur = -INFINITY; }
            if (lane == rk) my_idx = (float)bi;
        }

        out_probs[(size_t)tok * NUM_EXPERTS + lane] = (float)(sel ? exp(noisy - m) / sum : 0.0);
        if (lane < TOPK) out_idx[(size_t)tok * TOPK + lane] = my_idx;
    }
}

extern "C" void kernel_launch(void* const* d_in, const int* in_sizes, int n_in,
                              void* d_out, int out_size, void* d_ws, size_t ws_size,
                              hipStream_t stream) {
    const float* x   = (const float*)d_in[0];
    const float* eps = (const float*)d_in[1];
    const float* Wg  = (const float*)d_in[2];
    const float* bg  = (const float*)d_in[3];
    const float* Wn  = (const float*)d_in[4];
    const float* bn  = (const float*)d_in[5];

    float* out_probs = (float*)d_out;                                  // [N, E]
    float* out_idx   = (float*)d_out + (size_t)N_TOKENS * NUM_EXPERTS; // [N, K]

    float4* WT4 = (float4*)d_ws;    // 512 * 128 * 16 B = 1 MB

    wt_build_kernel<<<dim3(256), dim3(256), 0, stream>>>(Wg, Wn, WT4);

    dim3 grid(N_TOKENS / TOK_PER_BLOCK);   // 1024
    dim3 block(BLOCK_THREADS);             // 512
    noisy_topk_router_kernel<<<grid, block, 0, stream>>>(
        x, eps, WT4, bg, bn, out_probs, out_idx);
}